// Round 1
// 1513.119 us; speedup vs baseline: 3.2669x; 3.2669x over previous
//
#include <hip/hip_runtime.h>

// ---------------------------------------------------------------------------
// SimpleGCNTanh on MI355X — round 2: replace per-edge atomic scatter with
// CSR (dst-sorted) pull-gather, built once per launch.
// Pipeline:
//   CSR build: cnt[dst]++ (int atomics) -> prefix scan -> cursor fill
//   dinv = rsqrt(cnt+1)
//   3x GCNConv: hw = h@W (tiled fp32 GEMM) ;
//               per-node wave gather: h = tanh(sum_in hw[s]*dinv[s]*dinv[d]
//                                              + hw[d]*dinv[d]^2 + b)
//   h2 = tanh(h@W2+b2), h3 = tanh(h2@W3+b3)  (tiled GEMM + fused bias/tanh)
//   per-edge: e = [h3[src], h3[dst]] -> d_out[E*6:], out = e@Wcls+bcls
// Workspace (floats): dinv[N] | bufA[N*128] | bufB[N*128]   (~103 MB, same as r1)
// CSR temporaries (cnt/cursor/blkSum) alias bufA (dead during build);
// rowStart lives in d_out[0:N+1), csr_src in d_out[E*6:) — both regions are
// only written by the final edge_out kernel, after their last CSR read.
// ---------------------------------------------------------------------------

__global__ __launch_bounds__(256) void zero_int_kernel(int* __restrict__ p, int n) {
    int i = blockIdx.x * 256 + threadIdx.x;
    if (i < n) p[i] = 0;
}

__global__ __launch_bounds__(256) void deg_count_kernel(int* __restrict__ cnt,
                                                        const int* __restrict__ dst, int E) {
    int e = blockIdx.x * 256 + threadIdx.x;
    if (e < E) atomicAdd(&cnt[dst[e]], 1);
}

__global__ __launch_bounds__(256) void dinv_kernel(const int* __restrict__ cnt,
                                                   float* __restrict__ dinv, int n) {
    int i = blockIdx.x * 256 + threadIdx.x;
    if (i < n) dinv[i] = rsqrtf((float)cnt[i] + 1.0f);  // +1 for self-loop
}

// --- 3-kernel exclusive prefix scan of cnt[N] -> rowStart[N] (+cursor copy) ---

__global__ __launch_bounds__(256) void scan_blksum_kernel(const int* __restrict__ cnt,
                                                          int* __restrict__ blkSum, int N) {
    int i = blockIdx.x * 256 + threadIdx.x;
    int v = (i < N) ? cnt[i] : 0;
#pragma unroll
    for (int m = 32; m >= 1; m >>= 1) v += __shfl_xor(v, m, 64);
    __shared__ int wsum[4];
    if ((threadIdx.x & 63) == 0) wsum[threadIdx.x >> 6] = v;
    __syncthreads();
    if (threadIdx.x == 0) blkSum[blockIdx.x] = wsum[0] + wsum[1] + wsum[2] + wsum[3];
}

// single block: exclusive scan of blkSum[0..nb-1], nb <= 1024
__global__ __launch_bounds__(256) void scan_mid_kernel(int* __restrict__ blkSum, int nb) {
    int t = threadIdx.x;
    int base = t * 4;
    int v[4];
#pragma unroll
    for (int k = 0; k < 4; ++k) v[k] = (base + k < nb) ? blkSum[base + k] : 0;
    int tot = v[0] + v[1] + v[2] + v[3];
    int lane = t & 63, wv = t >> 6;
    int inc = tot;
#pragma unroll
    for (int m = 1; m < 64; m <<= 1) {
        int o = __shfl_up(inc, m, 64);
        if (lane >= m) inc += o;
    }
    __shared__ int wsum[4];
    if (lane == 63) wsum[wv] = inc;
    __syncthreads();
    int woff = 0;
    for (int k = 0; k < wv; ++k) woff += wsum[k];
    int run = woff + inc - tot;  // exclusive prefix of this thread's chunk
#pragma unroll
    for (int k = 0; k < 4; ++k) {
        if (base + k < nb) blkSum[base + k] = run;
        run += v[k];
    }
}

__global__ __launch_bounds__(256) void scan_finish_kernel(const int* __restrict__ cnt,
                                                          const int* __restrict__ blkSum,
                                                          int* __restrict__ rowStart,
                                                          int* __restrict__ cursor, int N, int E) {
    int i = blockIdx.x * 256 + threadIdx.x;
    int v = (i < N) ? cnt[i] : 0;
    int lane = threadIdx.x & 63, wv = threadIdx.x >> 6;
    int inc = v;
#pragma unroll
    for (int m = 1; m < 64; m <<= 1) {
        int o = __shfl_up(inc, m, 64);
        if (lane >= m) inc += o;
    }
    __shared__ int wsum[4];
    if (lane == 63) wsum[wv] = inc;
    __syncthreads();
    int woff = 0;
    for (int k = 0; k < wv; ++k) woff += wsum[k];
    int excl = blkSum[blockIdx.x] + woff + inc - v;
    if (i < N) {
        rowStart[i] = excl;
        cursor[i] = excl;
    }
    if (blockIdx.x == 0 && threadIdx.x == 0) rowStart[N] = E;
}

__global__ __launch_bounds__(256) void csr_fill_kernel(const int* __restrict__ src,
                                                       const int* __restrict__ dst,
                                                       int* __restrict__ cursor,
                                                       int* __restrict__ csr_src, int E) {
    int e = blockIdx.x * 256 + threadIdx.x;
    if (e < E) {
        int d = dst[e];
        int idx = atomicAdd(&cursor[d], 1);
        csr_src[idx] = src[e];
    }
}

// ---------------------------------------------------------------------------
// Tiled fp32 GEMM: Y = X[n,K] @ W[K,M]
// EPI 0: Y = XW                 (raw hw for the gather stage)
// EPI 1: Y = tanh(XW + bias)
// ---------------------------------------------------------------------------
template <int K, int M, int EPI>
__global__ __launch_bounds__(256) void gemm_kernel(const float* __restrict__ X,
                                                   const float* __restrict__ W,
                                                   float* __restrict__ Y,
                                                   const float* __restrict__ bias, int n) {
    constexpr int BK = 32;
    constexpr int TC = M / 4;      // threads along cols
    constexpr int TR = 256 / TC;   // threads along rows
    constexpr int R = TR * 4;      // rows per block

    __shared__ float xs[R * BK];
    __shared__ float ws[BK * M];

    const int t = threadIdx.x;
    const int tc = t % TC, tr = t / TC;
    const int c0 = tc * 4;
    const int r0 = tr * 4;
    const int row0 = blockIdx.x * R;

    float acc[4][4] = {};

    for (int k0 = 0; k0 < K; k0 += BK) {
        constexpr int XV = (R * BK) / (256 * 4);
#pragma unroll
        for (int i = 0; i < XV; ++i) {
            int idx = (t + i * 256) * 4;
            int rr = idx / BK, kk = idx % BK;
            int grow = row0 + rr;
            float4 v = make_float4(0.f, 0.f, 0.f, 0.f);
            if (grow < n) v = *(const float4*)&X[(size_t)grow * K + k0 + kk];
            *(float4*)&xs[idx] = v;
        }
        constexpr int WV = (BK * M) / (256 * 4);
#pragma unroll
        for (int i = 0; i < WV; ++i) {
            int idx = (t + i * 256) * 4;
            int kk = idx / M, mm = idx % M;
            *(float4*)&ws[idx] = *(const float4*)&W[(size_t)(k0 + kk) * M + mm];
        }
        __syncthreads();
#pragma unroll
        for (int kk = 0; kk < BK; kk += 4) {
            float4 xv[4], wv[4];
#pragma unroll
            for (int i = 0; i < 4; ++i) xv[i] = *(const float4*)&xs[(r0 + i) * BK + kk];
#pragma unroll
            for (int j = 0; j < 4; ++j) wv[j] = *(const float4*)&ws[(kk + j) * M + c0];
#pragma unroll
            for (int i = 0; i < 4; ++i) {
                const float* xp = (const float*)&xv[i];
#pragma unroll
                for (int j = 0; j < 4; ++j) {
                    const float xk = xp[j];
                    const float* wp = (const float*)&wv[j];
                    acc[i][0] += xk * wp[0];
                    acc[i][1] += xk * wp[1];
                    acc[i][2] += xk * wp[2];
                    acc[i][3] += xk * wp[3];
                }
            }
        }
        __syncthreads();
    }

#pragma unroll
    for (int i = 0; i < 4; ++i) {
        int grow = row0 + r0 + i;
        if (grow >= n) continue;
        float4 v = make_float4(acc[i][0], acc[i][1], acc[i][2], acc[i][3]);
        if (EPI == 1) {
            v.x = tanhf(v.x + bias[c0 + 0]);
            v.y = tanhf(v.y + bias[c0 + 1]);
            v.z = tanhf(v.z + bias[c0 + 2]);
            v.w = tanhf(v.w + bias[c0 + 3]);
        }
        *(float4*)&Y[(size_t)grow * M + c0] = v;
    }
}

// ---------------------------------------------------------------------------
// CSR pull aggregation, one wave per dst node, 64 lanes x float2 = 128 feats.
// h_out[d] = tanh( hw[d]*dinv[d]^2 + sum_{s in in(d)} hw[s]*dinv[s]*dinv[d] + b )
// 2-way unrolled so two 512B row gathers are in flight per wave.
// ---------------------------------------------------------------------------
__global__ __launch_bounds__(256) void gather_agg_kernel(const float* __restrict__ hw,
                                                         float* __restrict__ hout,
                                                         const int* __restrict__ rowStart,
                                                         const int* __restrict__ csr_src,
                                                         const float* __restrict__ dinv,
                                                         const float* __restrict__ bias, int N) {
    int gid = blockIdx.x * 256 + threadIdx.x;
    int node = gid >> 6;
    int lane = gid & 63;
    if (node >= N) return;

    int beg = rowStart[node];
    int end = rowStart[node + 1];
    float dd = dinv[node];

    float2 self = *(const float2*)&hw[(size_t)node * 128 + lane * 2];
    float d2 = dd * dd;
    float2 acc0 = make_float2(self.x * d2, self.y * d2);
    float2 acc1 = make_float2(0.f, 0.f);

    int j = beg;
    for (; j + 2 <= end; j += 2) {
        int s0 = csr_src[j];
        int s1 = csr_src[j + 1];
        float c0 = dinv[s0] * dd;
        float c1 = dinv[s1] * dd;
        float2 v0 = *(const float2*)&hw[(size_t)s0 * 128 + lane * 2];
        float2 v1 = *(const float2*)&hw[(size_t)s1 * 128 + lane * 2];
        acc0.x += v0.x * c0;
        acc0.y += v0.y * c0;
        acc1.x += v1.x * c1;
        acc1.y += v1.y * c1;
    }
    if (j < end) {
        int s0 = csr_src[j];
        float c0 = dinv[s0] * dd;
        float2 v0 = *(const float2*)&hw[(size_t)s0 * 128 + lane * 2];
        acc0.x += v0.x * c0;
        acc0.y += v0.y * c0;
    }

    float2 r;
    r.x = tanhf(acc0.x + acc1.x + bias[lane * 2 + 0]);
    r.y = tanhf(acc0.y + acc1.y + bias[lane * 2 + 1]);
    *(float2*)&hout[(size_t)node * 128 + lane * 2] = r;
}

// ---------------------------------------------------------------------------
// Final per-edge kernel: e = concat(h3[src], h3[dst]) (write to e_out),
// out = e @ Wcls + bcls.  32 threads per edge, shfl-xor reduction.
// ---------------------------------------------------------------------------
__global__ __launch_bounds__(256) void edge_out_kernel(const float* __restrict__ h3,
                                                       const int* __restrict__ src,
                                                       const int* __restrict__ dst,
                                                       const float* __restrict__ Wcls,
                                                       const float* __restrict__ bcls,
                                                       float* __restrict__ out,
                                                       float* __restrict__ e_out, int E) {
    __shared__ float wcl[64 * 6];
    __shared__ float bcl[6];
    for (int i = threadIdx.x; i < 64 * 6; i += 256) wcl[i] = Wcls[i];
    if (threadIdx.x < 6) bcl[threadIdx.x] = bcls[threadIdx.x];
    __syncthreads();

    int gid = blockIdx.x * 256 + threadIdx.x;
    int edge = gid >> 5;
    int c = gid & 31;
    if (edge >= E) return;
    int s = src[edge];
    int d = dst[edge];
    float2 v;
    if (c < 16)
        v = *(const float2*)&h3[(size_t)s * 32 + c * 2];
    else
        v = *(const float2*)&h3[(size_t)d * 32 + (c - 16) * 2];
    *(float2*)&e_out[(size_t)edge * 64 + c * 2] = v;

    float p[6];
#pragma unroll
    for (int j = 0; j < 6; ++j)
        p[j] = v.x * wcl[(c * 2) * 6 + j] + v.y * wcl[(c * 2 + 1) * 6 + j];
#pragma unroll
    for (int m = 16; m >= 1; m >>= 1) {
#pragma unroll
        for (int j = 0; j < 6; ++j) p[j] += __shfl_xor(p[j], m, 64);
    }
    if (c == 0) {
#pragma unroll
        for (int j = 0; j < 6; ++j) out[(size_t)edge * 6 + j] = p[j] + bcl[j];
    }
}

// ---------------------------------------------------------------------------

static inline int cdiv(long long a, long long b) { return (int)((a + b - 1) / b); }

extern "C" void kernel_launch(void* const* d_in, const int* in_sizes, int n_in,
                              void* d_out, int out_size, void* d_ws, size_t ws_size,
                              hipStream_t stream) {
    const int N = in_sizes[0] / 128;
    const int E = in_sizes[1] / 2;

    const float* x = (const float*)d_in[0];
    const int* ei = (const int*)d_in[1];
    const int* srcp = ei;
    const int* dstp = ei + E;
    const float* W1 = (const float*)d_in[3];
    const float* b1 = (const float*)d_in[4];
    const float* Wc = (const float*)d_in[5];
    const float* bc = (const float*)d_in[6];
    const float* W2 = (const float*)d_in[7];
    const float* b2 = (const float*)d_in[8];
    const float* W3 = (const float*)d_in[9];
    const float* b3 = (const float*)d_in[10];
    const float* Wcls = (const float*)d_in[11];
    const float* bcls = (const float*)d_in[12];

    float* wsf = (float*)d_ws;
    float* dinv = wsf;                          // N floats
    float* bufA = wsf + N;                      // N*128
    float* bufB = bufA + (size_t)N * 128;       // N*128

    float* out = (float*)d_out;                 // E*6
    float* e_out = out + (size_t)E * 6;         // E*64

    // CSR arrays stashed in regions that are dead until their last read:
    //  - temporaries in bufA (bufA first written by gather_agg of conv1)
    //  - persistent rowStart/csr_src in d_out (first written by edge_out, last kernel)
    int* cnt = (int*)bufA;                      // N ints  (temp)
    int* cursor = cnt + N;                      // N ints  (temp)
    int* blkSum = cursor + N;                   // <=1024 ints (temp)
    int* rowStart = (int*)out;                  // N+1 ints (read through conv3 gather)
    int* csr_src = (int*)e_out;                 // E ints   (read through conv3 gather)

    const int nb = cdiv(N, 256);

    // ---- CSR build + dinv ----
    zero_int_kernel<<<cdiv(N, 256), 256, 0, stream>>>(cnt, N);
    deg_count_kernel<<<cdiv(E, 256), 256, 0, stream>>>(cnt, dstp, E);
    dinv_kernel<<<cdiv(N, 256), 256, 0, stream>>>(cnt, dinv, N);
    scan_blksum_kernel<<<nb, 256, 0, stream>>>(cnt, blkSum, N);
    scan_mid_kernel<<<1, 256, 0, stream>>>(blkSum, nb);
    scan_finish_kernel<<<nb, 256, 0, stream>>>(cnt, blkSum, rowStart, cursor, N, E);
    csr_fill_kernel<<<cdiv(E, 256), 256, 0, stream>>>(srcp, dstp, cursor, csr_src, E);

    // ---- conv1: hw = x@W1 -> bufB ; gather+bias+tanh -> bufA ----
    gemm_kernel<128, 128, 0><<<cdiv(N, 32), 256, 0, stream>>>(x, W1, bufB, nullptr, N);
    gather_agg_kernel<<<cdiv((long long)N * 64, 256), 256, 0, stream>>>(bufB, bufA, rowStart,
                                                                        csr_src, dinv, b1, N);

    // ---- conv2, conv3 ----
    for (int i = 0; i < 2; ++i) {
        gemm_kernel<128, 128, 0><<<cdiv(N, 32), 256, 0, stream>>>(
            bufA, Wc + (size_t)i * 128 * 128, bufB, nullptr, N);
        gather_agg_kernel<<<cdiv((long long)N * 64, 256), 256, 0, stream>>>(
            bufB, bufA, rowStart, csr_src, dinv, bc + i * 128, N);
    }

    // ---- h2 = tanh(h@W2+b2) -> bufB (N x 64) ----
    gemm_kernel<128, 64, 1><<<cdiv(N, 64), 256, 0, stream>>>(bufA, W2, bufB, b2, N);
    // ---- h3 = tanh(h2@W3+b3) -> bufA (N x 32) ----
    gemm_kernel<64, 32, 1><<<cdiv(N, 128), 256, 0, stream>>>(bufB, W3, bufA, b3, N);

    // ---- per-edge outputs (overwrites the CSR stash in d_out) ----
    edge_out_kernel<<<cdiv((long long)E * 32, 256), 256, 0, stream>>>(bufA, srcp, dstp, Wcls, bcls,
                                                                      out, e_out, E);
}

// Round 2
// 1333.816 us; speedup vs baseline: 3.7061x; 1.1344x over previous
//
#include <hip/hip_runtime.h>

// ---------------------------------------------------------------------------
// SimpleGCNTanh on MI355X — round 3.
// Changes vs round 2:
//  * edge_out no longer does a 64-wide shfl dot per edge: out[e] = P1[src] +
//    P2[dst] + b, with P = h3 @ [Wcls_top | Wcls_bot] (N x 12) precomputed by
//    node_proj_kernel. edge_out is now a pure gather/copy (write-bound).
//  * GEMM epilogue EPI 0 writes Y = (X@W) * dinv[row]  (prescaled), so the
//    CSR gather is plain adds: h[d] = tanh(dinv[d]*(sum_s Y[s] + Y[d]) + b).
//  * gather_agg unrolled 4-way (4 row-gathers in flight per wave).
// Workspace (floats): dinv[N] | bufA[N*128] | bufB[N*128]
// CSR temporaries alias bufA; rowStart/csr_src live in d_out until edge_out.
// P (N x 12) lives in bufB after the last GEMM has consumed h2 from bufB.
// ---------------------------------------------------------------------------

__global__ __launch_bounds__(256) void zero_int_kernel(int* __restrict__ p, int n) {
    int i = blockIdx.x * 256 + threadIdx.x;
    if (i < n) p[i] = 0;
}

__global__ __launch_bounds__(256) void deg_count_kernel(int* __restrict__ cnt,
                                                        const int* __restrict__ dst, int E) {
    int e = blockIdx.x * 256 + threadIdx.x;
    if (e < E) atomicAdd(&cnt[dst[e]], 1);
}

__global__ __launch_bounds__(256) void dinv_kernel(const int* __restrict__ cnt,
                                                   float* __restrict__ dinv, int n) {
    int i = blockIdx.x * 256 + threadIdx.x;
    if (i < n) dinv[i] = rsqrtf((float)cnt[i] + 1.0f);  // +1 for self-loop
}

// --- 3-kernel exclusive prefix scan of cnt[N] -> rowStart[N] (+cursor copy) ---

__global__ __launch_bounds__(256) void scan_blksum_kernel(const int* __restrict__ cnt,
                                                          int* __restrict__ blkSum, int N) {
    int i = blockIdx.x * 256 + threadIdx.x;
    int v = (i < N) ? cnt[i] : 0;
#pragma unroll
    for (int m = 32; m >= 1; m >>= 1) v += __shfl_xor(v, m, 64);
    __shared__ int wsum[4];
    if ((threadIdx.x & 63) == 0) wsum[threadIdx.x >> 6] = v;
    __syncthreads();
    if (threadIdx.x == 0) blkSum[blockIdx.x] = wsum[0] + wsum[1] + wsum[2] + wsum[3];
}

// single block: exclusive scan of blkSum[0..nb-1], nb <= 1024
__global__ __launch_bounds__(256) void scan_mid_kernel(int* __restrict__ blkSum, int nb) {
    int t = threadIdx.x;
    int base = t * 4;
    int v[4];
#pragma unroll
    for (int k = 0; k < 4; ++k) v[k] = (base + k < nb) ? blkSum[base + k] : 0;
    int tot = v[0] + v[1] + v[2] + v[3];
    int lane = t & 63, wv = t >> 6;
    int inc = tot;
#pragma unroll
    for (int m = 1; m < 64; m <<= 1) {
        int o = __shfl_up(inc, m, 64);
        if (lane >= m) inc += o;
    }
    __shared__ int wsum[4];
    if (lane == 63) wsum[wv] = inc;
    __syncthreads();
    int woff = 0;
    for (int k = 0; k < wv; ++k) woff += wsum[k];
    int run = woff + inc - tot;  // exclusive prefix of this thread's chunk
#pragma unroll
    for (int k = 0; k < 4; ++k) {
        if (base + k < nb) blkSum[base + k] = run;
        run += v[k];
    }
}

__global__ __launch_bounds__(256) void scan_finish_kernel(const int* __restrict__ cnt,
                                                          const int* __restrict__ blkSum,
                                                          int* __restrict__ rowStart,
                                                          int* __restrict__ cursor, int N, int E) {
    int i = blockIdx.x * 256 + threadIdx.x;
    int v = (i < N) ? cnt[i] : 0;
    int lane = threadIdx.x & 63, wv = threadIdx.x >> 6;
    int inc = v;
#pragma unroll
    for (int m = 1; m < 64; m <<= 1) {
        int o = __shfl_up(inc, m, 64);
        if (lane >= m) inc += o;
    }
    __shared__ int wsum[4];
    if (lane == 63) wsum[wv] = inc;
    __syncthreads();
    int woff = 0;
    for (int k = 0; k < wv; ++k) woff += wsum[k];
    int excl = blkSum[blockIdx.x] + woff + inc - v;
    if (i < N) {
        rowStart[i] = excl;
        cursor[i] = excl;
    }
    if (blockIdx.x == 0 && threadIdx.x == 0) rowStart[N] = E;
}

__global__ __launch_bounds__(256) void csr_fill_kernel(const int* __restrict__ src,
                                                       const int* __restrict__ dst,
                                                       int* __restrict__ cursor,
                                                       int* __restrict__ csr_src, int E) {
    int e = blockIdx.x * 256 + threadIdx.x;
    if (e < E) {
        int d = dst[e];
        int idx = atomicAdd(&cursor[d], 1);
        csr_src[idx] = src[e];
    }
}

// ---------------------------------------------------------------------------
// Tiled fp32 GEMM: Y = X[n,K] @ W[K,M]
// EPI 0: Y = (XW) * dinv[row]        (prescaled hw for the gather stage)
// EPI 1: Y = tanh(XW + bias)
// ---------------------------------------------------------------------------
template <int K, int M, int EPI>
__global__ __launch_bounds__(256) void gemm_kernel(const float* __restrict__ X,
                                                   const float* __restrict__ W,
                                                   float* __restrict__ Y,
                                                   const float* __restrict__ bias,
                                                   const float* __restrict__ dinv, int n) {
    constexpr int BK = 32;
    constexpr int TC = M / 4;      // threads along cols
    constexpr int TR = 256 / TC;   // threads along rows
    constexpr int R = TR * 4;      // rows per block

    __shared__ float xs[R * BK];
    __shared__ float ws[BK * M];

    const int t = threadIdx.x;
    const int tc = t % TC, tr = t / TC;
    const int c0 = tc * 4;
    const int r0 = tr * 4;
    const int row0 = blockIdx.x * R;

    float acc[4][4] = {};

    for (int k0 = 0; k0 < K; k0 += BK) {
        constexpr int XV = (R * BK) / (256 * 4);
#pragma unroll
        for (int i = 0; i < XV; ++i) {
            int idx = (t + i * 256) * 4;
            int rr = idx / BK, kk = idx % BK;
            int grow = row0 + rr;
            float4 v = make_float4(0.f, 0.f, 0.f, 0.f);
            if (grow < n) v = *(const float4*)&X[(size_t)grow * K + k0 + kk];
            *(float4*)&xs[idx] = v;
        }
        constexpr int WV = (BK * M) / (256 * 4);
#pragma unroll
        for (int i = 0; i < WV; ++i) {
            int idx = (t + i * 256) * 4;
            int kk = idx / M, mm = idx % M;
            *(float4*)&ws[idx] = *(const float4*)&W[(size_t)(k0 + kk) * M + mm];
        }
        __syncthreads();
#pragma unroll
        for (int kk = 0; kk < BK; kk += 4) {
            float4 xv[4], wv[4];
#pragma unroll
            for (int i = 0; i < 4; ++i) xv[i] = *(const float4*)&xs[(r0 + i) * BK + kk];
#pragma unroll
            for (int j = 0; j < 4; ++j) wv[j] = *(const float4*)&ws[(kk + j) * M + c0];
#pragma unroll
            for (int i = 0; i < 4; ++i) {
                const float* xp = (const float*)&xv[i];
#pragma unroll
                for (int j = 0; j < 4; ++j) {
                    const float xk = xp[j];
                    const float* wp = (const float*)&wv[j];
                    acc[i][0] += xk * wp[0];
                    acc[i][1] += xk * wp[1];
                    acc[i][2] += xk * wp[2];
                    acc[i][3] += xk * wp[3];
                }
            }
        }
        __syncthreads();
    }

#pragma unroll
    for (int i = 0; i < 4; ++i) {
        int grow = row0 + r0 + i;
        if (grow >= n) continue;
        float4 v = make_float4(acc[i][0], acc[i][1], acc[i][2], acc[i][3]);
        if (EPI == 0) {
            float di = dinv[grow];
            v.x *= di;
            v.y *= di;
            v.z *= di;
            v.w *= di;
        } else {
            v.x = tanhf(v.x + bias[c0 + 0]);
            v.y = tanhf(v.y + bias[c0 + 1]);
            v.z = tanhf(v.z + bias[c0 + 2]);
            v.w = tanhf(v.w + bias[c0 + 3]);
        }
        *(float4*)&Y[(size_t)grow * M + c0] = v;
    }
}

// ---------------------------------------------------------------------------
// CSR pull aggregation, one wave per dst node, 64 lanes x float2 = 128 feats.
// Input hs = (h@W)*dinv (prescaled), so the loop body is plain adds:
//   h_out[d] = tanh( dinv[d] * (hs[d] + sum_{s in in(d)} hs[s]) + b )
// 4-way unrolled: four 512B row gathers in flight per wave.
// ---------------------------------------------------------------------------
__global__ __launch_bounds__(256) void gather_agg_kernel(const float* __restrict__ hs,
                                                         float* __restrict__ hout,
                                                         const int* __restrict__ rowStart,
                                                         const int* __restrict__ csr_src,
                                                         const float* __restrict__ dinv,
                                                         const float* __restrict__ bias, int N) {
    int gid = blockIdx.x * 256 + threadIdx.x;
    int node = gid >> 6;
    int lane = gid & 63;
    if (node >= N) return;

    int beg = rowStart[node];
    int end = rowStart[node + 1];
    float dd = dinv[node];
    const size_t off = (size_t)lane * 2;

    float2 a0 = *(const float2*)&hs[(size_t)node * 128 + off];  // self term
    float2 a1 = make_float2(0.f, 0.f);
    float2 a2 = make_float2(0.f, 0.f);
    float2 a3 = make_float2(0.f, 0.f);

    int j = beg;
    for (; j + 4 <= end; j += 4) {
        int s0 = csr_src[j];
        int s1 = csr_src[j + 1];
        int s2 = csr_src[j + 2];
        int s3 = csr_src[j + 3];
        float2 v0 = *(const float2*)&hs[(size_t)s0 * 128 + off];
        float2 v1 = *(const float2*)&hs[(size_t)s1 * 128 + off];
        float2 v2 = *(const float2*)&hs[(size_t)s2 * 128 + off];
        float2 v3 = *(const float2*)&hs[(size_t)s3 * 128 + off];
        a0.x += v0.x; a0.y += v0.y;
        a1.x += v1.x; a1.y += v1.y;
        a2.x += v2.x; a2.y += v2.y;
        a3.x += v3.x; a3.y += v3.y;
    }
    for (; j < end; ++j) {
        int s = csr_src[j];
        float2 v = *(const float2*)&hs[(size_t)s * 128 + off];
        a0.x += v.x; a0.y += v.y;
    }

    float sx = (a0.x + a1.x) + (a2.x + a3.x);
    float sy = (a0.y + a1.y) + (a2.y + a3.y);
    float2 r;
    r.x = tanhf(dd * sx + bias[lane * 2 + 0]);
    r.y = tanhf(dd * sy + bias[lane * 2 + 1]);
    *(float2*)&hout[(size_t)node * 128 + off] = r;
}

// ---------------------------------------------------------------------------
// Per-node classifier projection: P[n][0:6] = h3[n] @ Wcls[0:32],
//                                 P[n][6:12] = h3[n] @ Wcls[32:64].
// One thread per node; Wcls staged in LDS (uniform broadcast reads).
// ---------------------------------------------------------------------------
__global__ __launch_bounds__(256) void node_proj_kernel(const float* __restrict__ h3,
                                                        const float* __restrict__ Wcls,
                                                        float* __restrict__ P, int N) {
    __shared__ float w[64 * 6];
    for (int i = threadIdx.x; i < 64 * 6; i += 256) w[i] = Wcls[i];
    __syncthreads();
    int node = blockIdx.x * 256 + threadIdx.x;
    if (node >= N) return;
    const float* row = &h3[(size_t)node * 32];
    float p[12] = {};
#pragma unroll
    for (int k4 = 0; k4 < 32; k4 += 4) {
        float4 hv = *(const float4*)&row[k4];
        const float* hp = (const float*)&hv;
#pragma unroll
        for (int kk = 0; kk < 4; ++kk) {
            int k = k4 + kk;
            float h = hp[kk];
#pragma unroll
            for (int j = 0; j < 6; ++j) {
                p[j] += h * w[k * 6 + j];
                p[6 + j] += h * w[(32 + k) * 6 + j];
            }
        }
    }
#pragma unroll
    for (int j = 0; j < 12; j += 4)
        *(float4*)&P[(size_t)node * 12 + j] = make_float4(p[j], p[j + 1], p[j + 2], p[j + 3]);
}

// ---------------------------------------------------------------------------
// Final per-edge kernel: e = concat(h3[src], h3[dst]) -> e_out,
// out[e][j] = P[src][j] + P[dst][6+j] + bcls[j].   16 threads per edge.
// Pure gather/copy — no reductions.
// ---------------------------------------------------------------------------
__global__ __launch_bounds__(256) void edge_out_kernel(const float* __restrict__ h3,
                                                       const float* __restrict__ P,
                                                       const int* __restrict__ src,
                                                       const int* __restrict__ dst,
                                                       const float* __restrict__ bcls,
                                                       float* __restrict__ out,
                                                       float* __restrict__ e_out, int E) {
    __shared__ float bcl[6];
    if (threadIdx.x < 6) bcl[threadIdx.x] = bcls[threadIdx.x];
    __syncthreads();

    int gid = blockIdx.x * 256 + threadIdx.x;
    int edge = gid >> 4;
    int c = gid & 15;
    if (edge >= E) return;
    int s = src[edge];
    int d = dst[edge];
    float4 v;
    if (c < 8)
        v = *(const float4*)&h3[(size_t)s * 32 + c * 4];
    else
        v = *(const float4*)&h3[(size_t)d * 32 + (c - 8) * 4];
    *(float4*)&e_out[(size_t)edge * 64 + c * 4] = v;

    if (c < 6) {
        out[(size_t)edge * 6 + c] = P[(size_t)s * 12 + c] + P[(size_t)d * 12 + 6 + c] + bcl[c];
    }
}

// ---------------------------------------------------------------------------

static inline int cdiv(long long a, long long b) { return (int)((a + b - 1) / b); }

extern "C" void kernel_launch(void* const* d_in, const int* in_sizes, int n_in,
                              void* d_out, int out_size, void* d_ws, size_t ws_size,
                              hipStream_t stream) {
    const int N = in_sizes[0] / 128;
    const int E = in_sizes[1] / 2;

    const float* x = (const float*)d_in[0];
    const int* ei = (const int*)d_in[1];
    const int* srcp = ei;
    const int* dstp = ei + E;
    const float* W1 = (const float*)d_in[3];
    const float* b1 = (const float*)d_in[4];
    const float* Wc = (const float*)d_in[5];
    const float* bc = (const float*)d_in[6];
    const float* W2 = (const float*)d_in[7];
    const float* b2 = (const float*)d_in[8];
    const float* W3 = (const float*)d_in[9];
    const float* b3 = (const float*)d_in[10];
    const float* Wcls = (const float*)d_in[11];
    const float* bcls = (const float*)d_in[12];

    float* wsf = (float*)d_ws;
    float* dinv = wsf;                          // N floats
    float* bufA = wsf + N;                      // N*128
    float* bufB = bufA + (size_t)N * 128;       // N*128

    float* out = (float*)d_out;                 // E*6
    float* e_out = out + (size_t)E * 6;         // E*64

    // CSR arrays stashed in regions that are dead until their last read:
    //  - temporaries in bufA (bufA first written by gather_agg of conv1)
    //  - persistent rowStart/csr_src in d_out (first written by edge_out, last kernel)
    int* cnt = (int*)bufA;                      // N ints  (temp)
    int* cursor = cnt + N;                      // N ints  (temp)
    int* blkSum = cursor + N;                   // <=1024 ints (temp)
    int* rowStart = (int*)out;                  // N+1 ints (read through conv3 gather)
    int* csr_src = (int*)e_out;                 // E ints   (read through conv3 gather)

    const int nb = cdiv(N, 256);

    // ---- CSR build + dinv ----
    zero_int_kernel<<<cdiv(N, 256), 256, 0, stream>>>(cnt, N);
    deg_count_kernel<<<cdiv(E, 256), 256, 0, stream>>>(cnt, dstp, E);
    dinv_kernel<<<cdiv(N, 256), 256, 0, stream>>>(cnt, dinv, N);
    scan_blksum_kernel<<<nb, 256, 0, stream>>>(cnt, blkSum, N);
    scan_mid_kernel<<<1, 256, 0, stream>>>(blkSum, nb);
    scan_finish_kernel<<<nb, 256, 0, stream>>>(cnt, blkSum, rowStart, cursor, N, E);
    csr_fill_kernel<<<cdiv(E, 256), 256, 0, stream>>>(srcp, dstp, cursor, csr_src, E);

    // ---- conv1: hs = (x@W1)*dinv -> bufB ; gather+bias+tanh -> bufA ----
    gemm_kernel<128, 128, 0><<<cdiv(N, 32), 256, 0, stream>>>(x, W1, bufB, nullptr, dinv, N);
    gather_agg_kernel<<<cdiv((long long)N * 64, 256), 256, 0, stream>>>(bufB, bufA, rowStart,
                                                                        csr_src, dinv, b1, N);

    // ---- conv2, conv3 ----
    for (int i = 0; i < 2; ++i) {
        gemm_kernel<128, 128, 0><<<cdiv(N, 32), 256, 0, stream>>>(
            bufA, Wc + (size_t)i * 128 * 128, bufB, nullptr, dinv, N);
        gather_agg_kernel<<<cdiv((long long)N * 64, 256), 256, 0, stream>>>(
            bufB, bufA, rowStart, csr_src, dinv, bc + i * 128, N);
    }

    // ---- h2 = tanh(h@W2+b2) -> bufB (N x 64) ----
    gemm_kernel<128, 64, 1><<<cdiv(N, 64), 256, 0, stream>>>(bufA, W2, bufB, b2, nullptr, N);
    // ---- h3 = tanh(h2@W3+b3) -> bufA (N x 32) ----
    gemm_kernel<64, 32, 1><<<cdiv(N, 128), 256, 0, stream>>>(bufB, W3, bufA, b3, nullptr, N);

    // ---- P = h3 @ [Wcls_top | Wcls_bot] -> bufB (N x 12); h2 is dead ----
    node_proj_kernel<<<cdiv(N, 256), 256, 0, stream>>>(bufA, Wcls, bufB, N);

    // ---- per-edge outputs (overwrites the CSR stash in d_out) ----
    edge_out_kernel<<<cdiv((long long)E * 16, 256), 256, 0, stream>>>(bufA, bufB, srcp, dstp, bcls,
                                                                      out, e_out, E);
}

// Round 4
// 1205.183 us; speedup vs baseline: 4.1016x; 1.1067x over previous
//
#include <hip/hip_runtime.h>

// ---------------------------------------------------------------------------
// SimpleGCNTanh on MI355X — round 4b (compile fix of round 4).
//  * Fused conv kernel: per block of 32 dst nodes, CSR-gather the aggregated
//    rows (int16, prescaled by dinv) into LDS, then 32x128 @ 128x128 GEMM
//    + bias + tanh from LDS.  (S*h)W = S*(hW); no hs intermediate.
//  * edge_out uses nontemporal stores (via clang ext_vector float4) for the
//    448 MB streaming output so it doesn't thrash h3/P out of cache.
// Workspace (floats): dinv[N] | bufA[N*128] | bufB[N*128]
// ---------------------------------------------------------------------------

typedef float nvec4 __attribute__((ext_vector_type(4)));

__global__ __launch_bounds__(256) void zero_int_kernel(int* __restrict__ p, int n) {
    int i = blockIdx.x * 256 + threadIdx.x;
    if (i < n) p[i] = 0;
}

__global__ __launch_bounds__(256) void deg_count_kernel(int* __restrict__ cnt,
                                                        const int* __restrict__ dst, int E) {
    int e = blockIdx.x * 256 + threadIdx.x;
    if (e < E) atomicAdd(&cnt[dst[e]], 1);
}

__global__ __launch_bounds__(256) void dinv_kernel(const int* __restrict__ cnt,
                                                   float* __restrict__ dinv, int n) {
    int i = blockIdx.x * 256 + threadIdx.x;
    if (i < n) dinv[i] = rsqrtf((float)cnt[i] + 1.0f);  // +1 for self-loop
}

// --- 3-kernel exclusive prefix scan of cnt[N] -> rowStart[N] (+cursor copy) ---

__global__ __launch_bounds__(256) void scan_blksum_kernel(const int* __restrict__ cnt,
                                                          int* __restrict__ blkSum, int N) {
    int i = blockIdx.x * 256 + threadIdx.x;
    int v = (i < N) ? cnt[i] : 0;
#pragma unroll
    for (int m = 32; m >= 1; m >>= 1) v += __shfl_xor(v, m, 64);
    __shared__ int wsum[4];
    if ((threadIdx.x & 63) == 0) wsum[threadIdx.x >> 6] = v;
    __syncthreads();
    if (threadIdx.x == 0) blkSum[blockIdx.x] = wsum[0] + wsum[1] + wsum[2] + wsum[3];
}

// single block: exclusive scan of blkSum[0..nb-1], nb <= 1024
__global__ __launch_bounds__(256) void scan_mid_kernel(int* __restrict__ blkSum, int nb) {
    int t = threadIdx.x;
    int base = t * 4;
    int v[4];
#pragma unroll
    for (int k = 0; k < 4; ++k) v[k] = (base + k < nb) ? blkSum[base + k] : 0;
    int tot = v[0] + v[1] + v[2] + v[3];
    int lane = t & 63, wv = t >> 6;
    int inc = tot;
#pragma unroll
    for (int m = 1; m < 64; m <<= 1) {
        int o = __shfl_up(inc, m, 64);
        if (lane >= m) inc += o;
    }
    __shared__ int wsum[4];
    if (lane == 63) wsum[wv] = inc;
    __syncthreads();
    int woff = 0;
    for (int k = 0; k < wv; ++k) woff += wsum[k];
    int run = woff + inc - tot;  // exclusive prefix of this thread's chunk
#pragma unroll
    for (int k = 0; k < 4; ++k) {
        if (base + k < nb) blkSum[base + k] = run;
        run += v[k];
    }
}

__global__ __launch_bounds__(256) void scan_finish_kernel(const int* __restrict__ cnt,
                                                          const int* __restrict__ blkSum,
                                                          int* __restrict__ rowStart,
                                                          int* __restrict__ cursor, int N, int E) {
    int i = blockIdx.x * 256 + threadIdx.x;
    int v = (i < N) ? cnt[i] : 0;
    int lane = threadIdx.x & 63, wv = threadIdx.x >> 6;
    int inc = v;
#pragma unroll
    for (int m = 1; m < 64; m <<= 1) {
        int o = __shfl_up(inc, m, 64);
        if (lane >= m) inc += o;
    }
    __shared__ int wsum[4];
    if (lane == 63) wsum[wv] = inc;
    __syncthreads();
    int woff = 0;
    for (int k = 0; k < wv; ++k) woff += wsum[k];
    int excl = blkSum[blockIdx.x] + woff + inc - v;
    if (i < N) {
        rowStart[i] = excl;
        cursor[i] = excl;
    }
    if (blockIdx.x == 0 && threadIdx.x == 0) rowStart[N] = E;
}

__global__ __launch_bounds__(256) void csr_fill_kernel(const int* __restrict__ src,
                                                       const int* __restrict__ dst,
                                                       int* __restrict__ cursor,
                                                       int* __restrict__ csr_src, int E) {
    int e = blockIdx.x * 256 + threadIdx.x;
    if (e < E) {
        int d = dst[e];
        int idx = atomicAdd(&cursor[d], 1);
        csr_src[idx] = src[e];
    }
}

// ---------------------------------------------------------------------------
// Quantize x: xq[row][f] = rint(x[row][f] * dinv[row] * 4096), int16.
// ---------------------------------------------------------------------------
__global__ __launch_bounds__(256) void quantx_kernel(const float* __restrict__ x,
                                                     const float* __restrict__ dinv,
                                                     short* __restrict__ xq, int N) {
    int i = blockIdx.x * 256 + threadIdx.x;  // indexes float4 groups
    int total = N * 32;
    if (i >= total) return;
    int row = i >> 5;
    float s = dinv[row] * 4096.0f;
    float4 v = *(const float4*)&x[(size_t)i * 4];
    short4 q;
    q.x = (short)(int)rintf(fminf(fmaxf(v.x * s, -32767.f), 32767.f));
    q.y = (short)(int)rintf(fminf(fmaxf(v.y * s, -32767.f), 32767.f));
    q.z = (short)(int)rintf(fminf(fmaxf(v.z * s, -32767.f), 32767.f));
    q.w = (short)(int)rintf(fminf(fmaxf(v.w * s, -32767.f), 32767.f));
    *(short4*)&xq[(size_t)i * 4] = q;
}

// ---------------------------------------------------------------------------
// Fused GCN conv: per block of 32 dst nodes,
//  phase 1 (gather): xs[r] = dinv[d] * inv_scale * (hq[d] + sum_s hq[s])
//  phase 2 (GEMM):   Y = tanh(xs @ W + bias)
//  OUT_Q=1: store rint(Y * dinv[row] * 32768) as int16; OUT_Q=0: fp32.
// LDS: xs 16 KB + ws 16 KB = 32 KB.
// ---------------------------------------------------------------------------
#define LOADQ(S, AX, AY)                                                   \
    {                                                                      \
        unsigned u_ = *(const unsigned*)&hq[(size_t)(S)*128 + lane * 2];   \
        AX += (int)(short)(u_ & 0xffffu);                                  \
        AY += (int)(short)(u_ >> 16);                                      \
    }

template <int OUT_Q>
__global__ __launch_bounds__(256) void conv_kernel(const short* __restrict__ hq,
                                                   float inv_scale_in,
                                                   const float* __restrict__ W,
                                                   const float* __restrict__ bias,
                                                   void* __restrict__ h_out_v,
                                                   const int* __restrict__ rowStart,
                                                   const int* __restrict__ csr_src,
                                                   const float* __restrict__ dinv, int N) {
    __shared__ float xs[32 * 128];
    __shared__ float ws[32 * 128];
    const int t = threadIdx.x;
    const int wave = t >> 6, lane = t & 63;
    const int row0 = blockIdx.x * 32;

    // ---- phase 1: gather (each wave handles 8 of the 32 rows) ----
    for (int r = wave; r < 32; r += 4) {
        const int node = row0 + r;
        float fx = 0.f, fy = 0.f;
        if (node < N) {
            const int beg = rowStart[node];
            const int end = rowStart[node + 1];
            int ax0 = 0, ay0 = 0, ax1 = 0, ay1 = 0;
            int ax2 = 0, ay2 = 0, ax3 = 0, ay3 = 0;
            LOADQ(node, ax0, ay0)  // self term (prescaled in hq)
            int j = beg;
            for (; j + 8 <= end; j += 8) {
                int s0 = csr_src[j + 0], s1 = csr_src[j + 1];
                int s2 = csr_src[j + 2], s3 = csr_src[j + 3];
                int s4 = csr_src[j + 4], s5 = csr_src[j + 5];
                int s6 = csr_src[j + 6], s7 = csr_src[j + 7];
                LOADQ(s0, ax0, ay0)
                LOADQ(s1, ax1, ay1)
                LOADQ(s2, ax2, ay2)
                LOADQ(s3, ax3, ay3)
                LOADQ(s4, ax0, ay0)
                LOADQ(s5, ax1, ay1)
                LOADQ(s6, ax2, ay2)
                LOADQ(s7, ax3, ay3)
            }
            for (; j + 4 <= end; j += 4) {
                int s0 = csr_src[j + 0], s1 = csr_src[j + 1];
                int s2 = csr_src[j + 2], s3 = csr_src[j + 3];
                LOADQ(s0, ax0, ay0)
                LOADQ(s1, ax1, ay1)
                LOADQ(s2, ax2, ay2)
                LOADQ(s3, ax3, ay3)
            }
            for (; j < end; ++j) {
                int s0 = csr_src[j];
                LOADQ(s0, ax0, ay0)
            }
            float sc = dinv[node] * inv_scale_in;
            fx = (float)((ax0 + ax1) + (ax2 + ax3)) * sc;
            fy = (float)((ay0 + ay1) + (ay2 + ay3)) * sc;
        }
        xs[r * 128 + lane * 2 + 0] = fx;
        xs[r * 128 + lane * 2 + 1] = fy;
    }
    __syncthreads();

    // ---- phase 2: GEMM 32x128 @ 128x128 from LDS ----
    const int tc = t & 31, tr = t >> 5;
    const int c0 = tc * 4, r0 = tr * 4;
    float acc[4][4] = {};
    for (int k0 = 0; k0 < 128; k0 += 32) {
#pragma unroll
        for (int i = 0; i < 4; ++i) {
            int idx = (t + i * 256) * 4;
            int kk = idx >> 7, mm = idx & 127;
            *(float4*)&ws[idx] = *(const float4*)&W[(size_t)(k0 + kk) * 128 + mm];
        }
        __syncthreads();
#pragma unroll
        for (int kk = 0; kk < 32; kk += 4) {
            float4 xv[4], wv[4];
#pragma unroll
            for (int i = 0; i < 4; ++i) xv[i] = *(const float4*)&xs[(r0 + i) * 128 + k0 + kk];
#pragma unroll
            for (int jj = 0; jj < 4; ++jj) wv[jj] = *(const float4*)&ws[(kk + jj) * 128 + c0];
#pragma unroll
            for (int i = 0; i < 4; ++i) {
                const float* xp = (const float*)&xv[i];
#pragma unroll
                for (int jj = 0; jj < 4; ++jj) {
                    const float xk = xp[jj];
                    const float* wp = (const float*)&wv[jj];
                    acc[i][0] += xk * wp[0];
                    acc[i][1] += xk * wp[1];
                    acc[i][2] += xk * wp[2];
                    acc[i][3] += xk * wp[3];
                }
            }
        }
        __syncthreads();
    }

    float4 bv = *(const float4*)&bias[c0];
#pragma unroll
    for (int i = 0; i < 4; ++i) {
        int grow = row0 + r0 + i;
        if (grow >= N) continue;
        float4 v;
        v.x = tanhf(acc[i][0] + bv.x);
        v.y = tanhf(acc[i][1] + bv.y);
        v.z = tanhf(acc[i][2] + bv.z);
        v.w = tanhf(acc[i][3] + bv.w);
        if (OUT_Q) {
            float s = dinv[grow] * 32768.0f;
            short4 q;
            q.x = (short)(int)rintf(fminf(fmaxf(v.x * s, -32767.f), 32767.f));
            q.y = (short)(int)rintf(fminf(fmaxf(v.y * s, -32767.f), 32767.f));
            q.z = (short)(int)rintf(fminf(fmaxf(v.z * s, -32767.f), 32767.f));
            q.w = (short)(int)rintf(fminf(fmaxf(v.w * s, -32767.f), 32767.f));
            *(short4*)&((short*)h_out_v)[(size_t)grow * 128 + c0] = q;
        } else {
            *(float4*)&((float*)h_out_v)[(size_t)grow * 128 + c0] = v;
        }
    }
}

// ---------------------------------------------------------------------------
// Tiled fp32 GEMM (dense head): Y = tanh(X[n,K] @ W[K,M] + bias)
// ---------------------------------------------------------------------------
template <int K, int M>
__global__ __launch_bounds__(256) void gemm_kernel(const float* __restrict__ X,
                                                   const float* __restrict__ W,
                                                   float* __restrict__ Y,
                                                   const float* __restrict__ bias, int n) {
    constexpr int BK = 32;
    constexpr int TC = M / 4;
    constexpr int TR = 256 / TC;
    constexpr int R = TR * 4;

    __shared__ float xs[R * BK];
    __shared__ float ws[BK * M];

    const int t = threadIdx.x;
    const int tc = t % TC, tr = t / TC;
    const int c0 = tc * 4;
    const int r0 = tr * 4;
    const int row0 = blockIdx.x * R;

    float acc[4][4] = {};

    for (int k0 = 0; k0 < K; k0 += BK) {
        constexpr int XV = (R * BK) / (256 * 4);
#pragma unroll
        for (int i = 0; i < XV; ++i) {
            int idx = (t + i * 256) * 4;
            int rr = idx / BK, kk = idx % BK;
            int grow = row0 + rr;
            float4 v = make_float4(0.f, 0.f, 0.f, 0.f);
            if (grow < n) v = *(const float4*)&X[(size_t)grow * K + k0 + kk];
            *(float4*)&xs[idx] = v;
        }
        constexpr int WV = (BK * M) / (256 * 4);
#pragma unroll
        for (int i = 0; i < WV; ++i) {
            int idx = (t + i * 256) * 4;
            int kk = idx / M, mm = idx % M;
            *(float4*)&ws[idx] = *(const float4*)&W[(size_t)(k0 + kk) * M + mm];
        }
        __syncthreads();
#pragma unroll
        for (int kk = 0; kk < BK; kk += 4) {
            float4 xv[4], wv[4];
#pragma unroll
            for (int i = 0; i < 4; ++i) xv[i] = *(const float4*)&xs[(r0 + i) * BK + kk];
#pragma unroll
            for (int j = 0; j < 4; ++j) wv[j] = *(const float4*)&ws[(kk + j) * M + c0];
#pragma unroll
            for (int i = 0; i < 4; ++i) {
                const float* xp = (const float*)&xv[i];
#pragma unroll
                for (int j = 0; j < 4; ++j) {
                    const float xk = xp[j];
                    const float* wp = (const float*)&wv[j];
                    acc[i][0] += xk * wp[0];
                    acc[i][1] += xk * wp[1];
                    acc[i][2] += xk * wp[2];
                    acc[i][3] += xk * wp[3];
                }
            }
        }
        __syncthreads();
    }

#pragma unroll
    for (int i = 0; i < 4; ++i) {
        int grow = row0 + r0 + i;
        if (grow >= n) continue;
        float4 v;
        v.x = tanhf(acc[i][0] + bias[c0 + 0]);
        v.y = tanhf(acc[i][1] + bias[c0 + 1]);
        v.z = tanhf(acc[i][2] + bias[c0 + 2]);
        v.w = tanhf(acc[i][3] + bias[c0 + 3]);
        *(float4*)&Y[(size_t)grow * M + c0] = v;
    }
}

// ---------------------------------------------------------------------------
// Per-node classifier projection: P[n][0:6] = h3[n] @ Wcls[0:32],
//                                 P[n][6:12] = h3[n] @ Wcls[32:64].
// ---------------------------------------------------------------------------
__global__ __launch_bounds__(256) void node_proj_kernel(const float* __restrict__ h3,
                                                        const float* __restrict__ Wcls,
                                                        float* __restrict__ P, int N) {
    __shared__ float w[64 * 6];
    for (int i = threadIdx.x; i < 64 * 6; i += 256) w[i] = Wcls[i];
    __syncthreads();
    int node = blockIdx.x * 256 + threadIdx.x;
    if (node >= N) return;
    const float* row = &h3[(size_t)node * 32];
    float p[12] = {};
#pragma unroll
    for (int k4 = 0; k4 < 32; k4 += 4) {
        float4 hv = *(const float4*)&row[k4];
        const float* hp = (const float*)&hv;
#pragma unroll
        for (int kk = 0; kk < 4; ++kk) {
            int k = k4 + kk;
            float h = hp[kk];
#pragma unroll
            for (int j = 0; j < 6; ++j) {
                p[j] += h * w[k * 6 + j];
                p[6 + j] += h * w[(32 + k) * 6 + j];
            }
        }
    }
#pragma unroll
    for (int j = 0; j < 12; j += 4)
        *(float4*)&P[(size_t)node * 12 + j] = make_float4(p[j], p[j + 1], p[j + 2], p[j + 3]);
}

// ---------------------------------------------------------------------------
// Final per-edge kernel: e = concat(h3[src], h3[dst]) -> e_out (nontemporal),
// out[e][j] = P[src][j] + P[dst][6+j] + bcls[j].   16 threads per edge.
// ---------------------------------------------------------------------------
__global__ __launch_bounds__(256) void edge_out_kernel(const float* __restrict__ h3,
                                                       const float* __restrict__ P,
                                                       const int* __restrict__ src,
                                                       const int* __restrict__ dst,
                                                       const float* __restrict__ bcls,
                                                       float* __restrict__ out,
                                                       float* __restrict__ e_out, int E) {
    __shared__ float bcl[6];
    if (threadIdx.x < 6) bcl[threadIdx.x] = bcls[threadIdx.x];
    __syncthreads();

    int gid = blockIdx.x * 256 + threadIdx.x;
    int edge = gid >> 4;
    int c = gid & 15;
    if (edge >= E) return;
    int s = src[edge];
    int d = dst[edge];
    nvec4 v;
    if (c < 8)
        v = *(const nvec4*)&h3[(size_t)s * 32 + c * 4];
    else
        v = *(const nvec4*)&h3[(size_t)d * 32 + (c - 8) * 4];
    __builtin_nontemporal_store(v, (nvec4*)&e_out[(size_t)edge * 64 + c * 4]);

    if (c < 6) {
        float r = P[(size_t)s * 12 + c] + P[(size_t)d * 12 + 6 + c] + bcl[c];
        __builtin_nontemporal_store(r, &out[(size_t)edge * 6 + c]);
    }
}

// ---------------------------------------------------------------------------

static inline int cdiv(long long a, long long b) { return (int)((a + b - 1) / b); }

extern "C" void kernel_launch(void* const* d_in, const int* in_sizes, int n_in,
                              void* d_out, int out_size, void* d_ws, size_t ws_size,
                              hipStream_t stream) {
    const int N = in_sizes[0] / 128;
    const int E = in_sizes[1] / 2;

    const float* x = (const float*)d_in[0];
    const int* ei = (const int*)d_in[1];
    const int* srcp = ei;
    const int* dstp = ei + E;
    const float* W1 = (const float*)d_in[3];
    const float* b1 = (const float*)d_in[4];
    const float* Wc = (const float*)d_in[5];
    const float* bc = (const float*)d_in[6];
    const float* W2 = (const float*)d_in[7];
    const float* b2 = (const float*)d_in[8];
    const float* W3 = (const float*)d_in[9];
    const float* b3 = (const float*)d_in[10];
    const float* Wcls = (const float*)d_in[11];
    const float* bcls = (const float*)d_in[12];

    float* wsf = (float*)d_ws;
    float* dinv = wsf;                          // N floats
    float* bufA = wsf + N;                      // N*128 floats
    float* bufB = bufA + (size_t)N * 128;       // N*128 floats

    float* out = (float*)d_out;                 // E*6
    float* e_out = out + (size_t)E * 6;         // E*64

    // CSR arrays in dead regions:
    //  - temporaries in bufA (bufA first written by conv1's output)
    //  - rowStart/csr_src in d_out (first written by edge_out, the last kernel;
    //    last read by conv3's gather)
    int* cnt = (int*)bufA;                      // N ints  (temp)
    int* cursor = cnt + N;                      // N ints  (temp)
    int* blkSum = cursor + N;                   // <=1024 ints (temp)
    int* rowStart = (int*)out;                  // N+1 ints
    int* csr_src = (int*)e_out;                 // E ints

    // int16 buffers alias the fp32 workspace
    short* xq = (short*)bufB;                   // N*128 int16 (25.6 MB)
    short* q1 = (short*)bufA;                   // conv1 out
    short* q2 = (short*)bufB;                   // conv2 out (xq dead by then)
    float* hC = bufA;                           // conv3 out fp32 (q1 dead)

    const int nb = cdiv(N, 256);

    // ---- CSR build + dinv ----
    zero_int_kernel<<<cdiv(N, 256), 256, 0, stream>>>(cnt, N);
    deg_count_kernel<<<cdiv(E, 256), 256, 0, stream>>>(cnt, dstp, E);
    dinv_kernel<<<cdiv(N, 256), 256, 0, stream>>>(cnt, dinv, N);
    scan_blksum_kernel<<<nb, 256, 0, stream>>>(cnt, blkSum, N);
    scan_mid_kernel<<<1, 256, 0, stream>>>(blkSum, nb);
    scan_finish_kernel<<<nb, 256, 0, stream>>>(cnt, blkSum, rowStart, cursor, N, E);
    csr_fill_kernel<<<cdiv(E, 256), 256, 0, stream>>>(srcp, dstp, cursor, csr_src, E);

    // ---- quantize x (prescaled by dinv) ----
    quantx_kernel<<<cdiv((long long)N * 32, 256), 256, 0, stream>>>(x, dinv, xq, N);

    // ---- fused convs ----
    conv_kernel<1><<<cdiv(N, 32), 256, 0, stream>>>(xq, 1.0f / 4096.0f, W1, b1, q1, rowStart,
                                                    csr_src, dinv, N);
    conv_kernel<1><<<cdiv(N, 32), 256, 0, stream>>>(q1, 1.0f / 32768.0f, Wc, bc, q2, rowStart,
                                                    csr_src, dinv, N);
    conv_kernel<0><<<cdiv(N, 32), 256, 0, stream>>>(q2, 1.0f / 32768.0f, Wc + (size_t)128 * 128,
                                                    bc + 128, hC, rowStart, csr_src, dinv, N);

    // ---- dense head: h2 = tanh(hC@W2+b2) -> bufB (N x 64) ----
    gemm_kernel<128, 64><<<cdiv(N, 64), 256, 0, stream>>>(hC, W2, bufB, b2, N);
    // ---- h3 = tanh(h2@W3+b3) -> bufA (N x 32) (hC dead) ----
    gemm_kernel<64, 32><<<cdiv(N, 128), 256, 0, stream>>>(bufB, W3, bufA, b3, N);

    // ---- P = h3 @ [Wcls_top | Wcls_bot] -> bufB (N x 12) ----
    node_proj_kernel<<<cdiv(N, 256), 256, 0, stream>>>(bufA, Wcls, bufB, N);

    // ---- per-edge outputs (overwrites the CSR stash in d_out) ----
    edge_out_kernel<<<cdiv((long long)E * 16, 256), 256, 0, stream>>>(bufA, bufB, srcp, dstp, bcls,
                                                                      out, e_out, E);
}